// Round 4
// baseline (751.118 us; speedup 1.0000x reference)
//
#include <hip/hip_runtime.h>

namespace {

constexpr int N_ENTITY = 50000;
constexpr int NR2      = 1000;     // 2 * num_relations
constexpr int NE       = 600000;
constexpr int D        = 128;
constexpr float BN_EPS = 1e-5f;

// ---- workspace layout (units of 4 bytes) ----
constexpr size_t OFF_YF   = 0;                     // 3,200,000 (bf16 pairs)
constexpr size_t OFF_YB   = OFF_YF + 3200000;      // 3,200,000
constexpr size_t OFF_ZF   = OFF_YB + 3200000;      // 64,000
constexpr size_t OFF_ZB   = OFF_ZF + 64000;        // 64,000
constexpr size_t OFF_WPK  = OFF_ZB + 64000;        // 24,576
constexpr size_t OFF_WRT  = OFF_WPK + 24576;       // 16,384
constexpr size_t OFF_SLW  = OFF_WRT + 16384;       // 256
constexpr size_t OFF_DEG0 = OFF_SLW + 256;         // 50,048
constexpr size_t OFF_DEG1 = OFF_DEG0 + 50048;      // 50,048
constexpr size_t OFF_OFF0 = OFF_DEG1 + 50048;      // 50,176
constexpr size_t OFF_OFF1 = OFF_OFF0 + 50176;      // 50,176
constexpr size_t OFF_CUR0 = OFF_OFF1 + 50176;      // 50,048
constexpr size_t OFF_CUR1 = OFF_CUR0 + 50048;      // 50,048
constexpr size_t OFF_RDG0 = OFF_CUR1 + 50048;      // 50,048 f32
constexpr size_t OFF_RDG1 = OFF_RDG0 + 50048;      // 50,048 f32
constexpr size_t OFF_EL0  = OFF_RDG1 + 50048;      // 1,200,128 (uint2)
constexpr size_t OFF_EL1  = OFF_EL0 + 1200128;     // 1,200,128
constexpr size_t OFF_PART = OFF_EL1 + 1200128;     // 256
constexpr size_t OFF_KSH  = OFF_PART + 256;        // 256

} // namespace

typedef __attribute__((ext_vector_type(8))) short bf16x8;
typedef __attribute__((ext_vector_type(4))) float f32x4;

__device__ inline unsigned f2bf(float x) {
  unsigned u = __float_as_uint(x);
  return (u + 0x7FFFu + ((u >> 16) & 1u)) >> 16;   // RNE
}
__device__ inline unsigned pack2bf(float a, float b) { return f2bf(a) | (f2bf(b) << 16); }
__device__ inline float bflo(unsigned v) { return __uint_as_float(v << 16); }
__device__ inline float bfhi(unsigned v) { return __uint_as_float(v & 0xFFFF0000u); }

// slice(e) in [0,8): even split of entity range; MUST match between count and fill
__device__ inline int slice_of(int e) { return (int)(((unsigned)e * 41u) >> 18); }

// ---------------- degree counting, XCD-sliced ----------------
__global__ __launch_bounds__(256) void k_countP(const int* __restrict__ esrc,
                                                const int* __restrict__ etgt,
                                                unsigned* __restrict__ deg0,
                                                unsigned* __restrict__ deg1) {
  const int slice = blockIdx.x & 7;
  const int sub = blockIdx.x >> 3;
  const int nsub = gridDim.x >> 3;
  for (int i = sub * 256 + threadIdx.x; i < NE; i += nsub * 256) {
    int s = esrc[i];
    if (slice_of(s) == slice) atomicAdd(&deg0[s], 1u);
    int t = etgt[i];
    if (slice_of(t) == slice) atomicAdd(&deg1[t], 1u);
  }
}

// ---------------- fused single-WG prefix scan (both rows) ----------------
__global__ __launch_bounds__(1024) void k_scanF(
    const unsigned* __restrict__ deg0, const unsigned* __restrict__ deg1,
    unsigned* __restrict__ off0, unsigned* __restrict__ off1,
    unsigned* __restrict__ cur0, unsigned* __restrict__ cur1,
    float* __restrict__ rdeg0, float* __restrict__ rdeg1) {
  __shared__ unsigned wtot[16], wpre[16];
  const int tid = threadIdx.x;
  const int lane = tid & 63, wid = tid >> 6;
  constexpr int PER = (N_ENTITY + 1023) / 1024;  // 49
  for (int row = 0; row < 2; ++row) {
    const unsigned* deg = row ? deg1 : deg0;
    unsigned* off = row ? off1 : off0;
    unsigned* cur = row ? cur1 : cur0;
    float* rdeg = row ? rdeg1 : rdeg0;
    int start = tid * PER;
    int end = start + PER; if (end > N_ENTITY) end = N_ENTITY;
    unsigned sum = 0;
    for (int i = start; i < end; ++i) sum += deg[i];
    // wave inclusive scan of sums
    unsigned incl = sum;
#pragma unroll
    for (int d = 1; d < 64; d <<= 1) {
      unsigned nv = __shfl_up(incl, d, 64);
      if (lane >= d) incl += nv;
    }
    if (lane == 63) wtot[wid] = incl;
    __syncthreads();
    if (wid == 0 && lane < 16) {
      unsigned v = wtot[lane];
      unsigned ic = v;
#pragma unroll
      for (int d = 1; d < 16; d <<= 1) {
        unsigned nv = __shfl_up(ic, d, 64);
        if (lane >= d) ic += nv;
      }
      wpre[lane] = ic - v;
    }
    __syncthreads();
    unsigned run = wpre[wid] + incl - sum;
    for (int i = start; i < end; ++i) {
      unsigned dv = deg[i];
      off[i] = run;
      cur[i] = run;
      rdeg[i] = rsqrtf((float)dv);
      run += dv;
    }
    if (tid == 0) off[N_ENTITY] = (unsigned)NE;
    __syncthreads();
  }
}

// ---------------- CSR fill, XCD-sliced scatter ----------------
__global__ __launch_bounds__(256) void k_fillP(
    const int* __restrict__ esrc, const int* __restrict__ etgt,
    const int* __restrict__ etype,
    const float* __restrict__ rdeg0, const float* __restrict__ rdeg1,
    unsigned* __restrict__ cur0, unsigned* __restrict__ cur1,
    uint2* __restrict__ el0, uint2* __restrict__ el1) {
  const int slice = blockIdx.x & 7;
  const int sub = blockIdx.x >> 3;
  const int nsub = gridDim.x >> 3;
  for (int i = sub * 256 + threadIdx.x; i < NE; i += nsub * 256) {
    int s = esrc[i], t = etgt[i];
    bool ws = (slice_of(s) == slice), wt = (slice_of(t) == slice);
    if (!(ws || wt)) continue;
    int et = etype[i];
    float w = rdeg0[s] * rdeg1[t];
    unsigned wb = __float_as_uint(w);
    if (wt) {
      unsigned p = atomicAdd(&cur1[t], 1u);
      el1[p] = make_uint2(((unsigned)s << 10) | (unsigned)(2 * et), wb);
    }
    if (ws) {
      unsigned p = atomicAdd(&cur0[s], 1u);
      el0[p] = make_uint2(((unsigned)t << 10) | (unsigned)(2 * et + 1), wb);
    }
  }
}

// ---------------- fused prep: w_rel transpose + self_loop@w_loop + weight frag-pack ----------------
__global__ void k_prep(const float* __restrict__ wl, const float* __restrict__ wf,
                       const float* __restrict__ wb, const float* __restrict__ wrel,
                       const float* __restrict__ sl,
                       unsigned* __restrict__ wpk, float* __restrict__ wrT,
                       float* __restrict__ slw) {
  const int b = blockIdx.x;
  const int t = threadIdx.x;
  if (b < 64) {
    int i = b * 256 + t;
    wrT[(i & 127) * D + (i >> 7)] = wrel[i];
  } else if (b == 64) {
    if (t < 128) {
      float a = 0.f;
      for (int k = 0; k < D; ++k) a = fmaf(sl[k], wl[k * D + t], a);
      slw[t] = a;
    }
  } else {
    int idx = (b - 65) * 256 + t;   // < 6144
    int w = idx / 2048, rem = idx % 2048;
    int frag = rem / 64, l = rem % 64;
    int ct = frag >> 2, kf = frag & 3;
    const float* W = (w == 0) ? wl : (w == 1) ? wf : wb;
    int krow = kf * 32 + (l >> 4) * 8;
    int col = ct * 16 + (l & 15);
    unsigned base = (unsigned)(w * 8192 + (frag * 64 + l) * 4);
#pragma unroll
    for (int j = 0; j < 8; j += 2) {
      float a = W[(krow + j) * D + col];
      float bb = W[(krow + j + 1) * D + col];
      wpk[base + (j >> 1)] = pack2bf(a, bb);
    }
  }
}

// ---------------- small GEMM: x_r @ {w_fwd, w_bwd, w_rel^T} ----------------
__global__ __launch_bounds__(256) void k_xr(
    const float* __restrict__ xr, const float* __restrict__ wf,
    const float* __restrict__ wb, const float* __restrict__ wrT,
    unsigned* __restrict__ Zf, unsigned* __restrict__ Zb, float* __restrict__ xrnew) {
  __shared__ float xs[8 * 132];
  const int t = threadIdx.x;
  const int tile = blockIdx.x * 8;
  for (int f = t * 4; f < 8 * 128; f += 1024) {
    int rr = f >> 7, kk = f & 127;
    *(float4*)(xs + rr * 132 + kk) = *(const float4*)(xr + (size_t)(tile + rr) * D + kk);
  }
  __syncthreads();
  const int c4 = (t & 31) * 4;
  const int rs = t >> 5;  // 0..7
  const int row = tile + rs;
  float4 af = make_float4(0, 0, 0, 0), ab = make_float4(0, 0, 0, 0), ar = make_float4(0, 0, 0, 0);
#pragma unroll 4
  for (int k = 0; k < 128; ++k) {
    float x = xs[rs * 132 + k];
    float4 f4 = *(const float4*)(wf + k * D + c4);
    float4 b4 = *(const float4*)(wb + k * D + c4);
    float4 r4 = *(const float4*)(wrT + k * D + c4);
    af.x = fmaf(x, f4.x, af.x); af.y = fmaf(x, f4.y, af.y);
    af.z = fmaf(x, f4.z, af.z); af.w = fmaf(x, f4.w, af.w);
    ab.x = fmaf(x, b4.x, ab.x); ab.y = fmaf(x, b4.y, ab.y);
    ab.z = fmaf(x, b4.z, ab.z); ab.w = fmaf(x, b4.w, ab.w);
    ar.x = fmaf(x, r4.x, ar.x); ar.y = fmaf(x, r4.y, ar.y);
    ar.z = fmaf(x, r4.z, ar.z); ar.w = fmaf(x, r4.w, ar.w);
  }
  uint2 pf = make_uint2(pack2bf(af.x, af.y), pack2bf(af.z, af.w));
  uint2 pb = make_uint2(pack2bf(ab.x, ab.y), pack2bf(ab.z, ab.w));
  *(uint2*)(Zf + (size_t)row * 64 + (c4 >> 1)) = pf;
  *(uint2*)(Zb + (size_t)row * 64 + (c4 >> 1)) = pb;
  *(float4*)(xrnew + (size_t)row * D + c4) = ar;
}

// ---------------- big GEMM via MFMA: x_e @ {w_loop, w_fwd, w_bwd} ----------------
__global__ __launch_bounds__(256) void k_gemm3m(
    const float* __restrict__ xe, const unsigned* __restrict__ wpk,
    const float* __restrict__ slw, float* __restrict__ outRaw,
    unsigned* __restrict__ Yf, unsigned* __restrict__ Yb) {
  __shared__ float lds[64 * 140];
  const int tid = threadIdx.x;
  const int wv = tid >> 6, l = tid & 63;
  const int tile = blockIdx.x * 64;
  const int arow = tile + wv * 16 + (l & 15);
  const int arc = (arow < N_ENTITY) ? arow : (N_ENTITY - 1);
  const int kbase = (l >> 4) * 8;

  bf16x8 a[4];
#pragma unroll
  for (int kf = 0; kf < 4; ++kf) {
    const float* src = xe + (size_t)arc * D + kf * 32 + kbase;
    float4 lo = *(const float4*)(src);
    float4 hi = *(const float4*)(src + 4);
    union { bf16x8 v; unsigned u[4]; } cv;
    cv.u[0] = pack2bf(lo.x, lo.y);
    cv.u[1] = pack2bf(lo.z, lo.w);
    cv.u[2] = pack2bf(hi.x, hi.y);
    cv.u[3] = pack2bf(hi.z, hi.w);
    a[kf] = cv.v;
  }

  for (int widx = 0; widx < 3; ++widx) {
    const unsigned* wbase = wpk + widx * 8192;
#pragma unroll
    for (int ct = 0; ct < 8; ++ct) {
      f32x4 acc = {0.f, 0.f, 0.f, 0.f};
#pragma unroll
      for (int kf = 0; kf < 4; ++kf) {
        const bf16x8 b = *(const bf16x8*)(wbase + ((ct * 4 + kf) * 64 + l) * 4);
        acc = __builtin_amdgcn_mfma_f32_16x16x32_bf16(a[kf], b, acc, 0, 0, 0);
      }
      const int rbase = wv * 16 + (l >> 4) * 4;
      const int cc = ct * 16 + (l & 15);
#pragma unroll
      for (int j = 0; j < 4; ++j) lds[(rbase + j) * 140 + cc] = acc[j];
    }
    __syncthreads();
    for (int f = tid; f < 64 * 32; f += 256) {
      int row = f >> 5, c4 = (f & 31) * 4;
      int g = tile + row;
      if (g < N_ENTITY) {
        float4 v = *(float4*)(lds + row * 140 + c4);
        if (widx == 0) {
          float4 s = *(const float4*)(slw + c4);
          float4 o = make_float4(v.x - s.x, v.y - s.y, v.z - s.z, v.w - s.w);
          *(float4*)(outRaw + (size_t)g * D + c4) = o;
        } else {
          uint2 p = make_uint2(pack2bf(v.x, v.y), pack2bf(v.z, v.w));
          unsigned* dst = ((widx == 1) ? Yf : Yb) + (size_t)g * 64 + (c4 >> 1);
          *(uint2*)dst = p;
        }
      }
    }
    __syncthreads();
  }
}

// ---------------- per-entity edge aggregation, 4x unrolled ----------------
__device__ inline void gather_dir(const unsigned* __restrict__ Y,
                                  const unsigned* __restrict__ Z,
                                  const uint2* __restrict__ el,
                                  unsigned b, unsigned e, int lane, float2& acc) {
  for (unsigned base = b; base < e; base += 64) {
    int cnt = (int)((e - base < 64u) ? (e - base) : 64u);
    uint2 ed = make_uint2(0u, 0u);
    if (lane < cnt) ed = el[base + lane];
    int i = 0;
    for (; i + 4 <= cnt; i += 4) {
      unsigned pk0 = __shfl(ed.x, i, 64);     float w0 = __uint_as_float(__shfl(ed.y, i, 64));
      unsigned pk1 = __shfl(ed.x, i + 1, 64); float w1 = __uint_as_float(__shfl(ed.y, i + 1, 64));
      unsigned pk2 = __shfl(ed.x, i + 2, 64); float w2 = __uint_as_float(__shfl(ed.y, i + 2, 64));
      unsigned pk3 = __shfl(ed.x, i + 3, 64); float w3 = __uint_as_float(__shfl(ed.y, i + 3, 64));
      unsigned y0 = Y[(size_t)(pk0 >> 10) * 64 + lane];
      unsigned z0 = Z[(size_t)(pk0 & 1023u) * 64 + lane];
      unsigned y1 = Y[(size_t)(pk1 >> 10) * 64 + lane];
      unsigned z1 = Z[(size_t)(pk1 & 1023u) * 64 + lane];
      unsigned y2 = Y[(size_t)(pk2 >> 10) * 64 + lane];
      unsigned z2 = Z[(size_t)(pk2 & 1023u) * 64 + lane];
      unsigned y3 = Y[(size_t)(pk3 >> 10) * 64 + lane];
      unsigned z3 = Z[(size_t)(pk3 & 1023u) * 64 + lane];
      acc.x = fmaf(w0, bflo(y0) - bflo(z0), acc.x);
      acc.y = fmaf(w0, bfhi(y0) - bfhi(z0), acc.y);
      acc.x = fmaf(w1, bflo(y1) - bflo(z1), acc.x);
      acc.y = fmaf(w1, bfhi(y1) - bfhi(z1), acc.y);
      acc.x = fmaf(w2, bflo(y2) - bflo(z2), acc.x);
      acc.y = fmaf(w2, bfhi(y2) - bfhi(z2), acc.y);
      acc.x = fmaf(w3, bflo(y3) - bflo(z3), acc.x);
      acc.y = fmaf(w3, bfhi(y3) - bfhi(z3), acc.y);
    }
    for (; i < cnt; ++i) {
      unsigned pk = __shfl(ed.x, i, 64);
      float w = __uint_as_float(__shfl(ed.y, i, 64));
      unsigned y = Y[(size_t)(pk >> 10) * 64 + lane];
      unsigned z = Z[(size_t)(pk & 1023u) * 64 + lane];
      acc.x = fmaf(w, bflo(y) - bflo(z), acc.x);
      acc.y = fmaf(w, bfhi(y) - bfhi(z), acc.y);
    }
  }
}

// grid is exactly N_ENTITY waves (no early-out; all threads reach barriers)
__global__ __launch_bounds__(256) void k_gather(
    const unsigned* __restrict__ Yf, const unsigned* __restrict__ Yb,
    const unsigned* __restrict__ Zf, const unsigned* __restrict__ Zb,
    const unsigned* __restrict__ off0, const unsigned* __restrict__ off1,
    const uint2* __restrict__ el0, const uint2* __restrict__ el1,
    float* __restrict__ out, float* __restrict__ part) {
  const int tid = threadIdx.x;
  const int lane = tid & 63;
  const int n = (int)((blockIdx.x * blockDim.x + tid) >> 6);
  const size_t rowoff = (size_t)n * D + lane * 2;
  float2 acc = *(const float2*)(out + rowoff);

  gather_dir(Yf, Zf, el1, off1[n], off1[n + 1], lane, acc);
  gather_dir(Yb, Zb, el0, off0[n], off0[n + 1], lane, acc);

  *(float2*)(out + rowoff) = acc;

  // fused BN partial sums (block-level LDS reduce, then one atomic per column)
  __shared__ float ssum[128], ssq[128];
  if (tid < 128) { ssum[tid] = 0.f; ssq[tid] = 0.f; }
  __syncthreads();
  const int c = lane * 2;
  atomicAdd(&ssum[c], acc.x);
  atomicAdd(&ssum[c + 1], acc.y);
  atomicAdd(&ssq[c], acc.x * acc.x);
  atomicAdd(&ssq[c + 1], acc.y * acc.y);
  __syncthreads();
  if (tid < 128) {
    atomicAdd(&part[tid], ssum[tid]);
    atomicAdd(&part[128 + tid], ssq[tid]);
  }
}

// ---------------- BN coefficients + finalize ----------------
__global__ void k_stats2(const float* __restrict__ part, const float* __restrict__ gamma,
                         const float* __restrict__ beta, float* __restrict__ ksh) {
  const int t = threadIdx.x;  // 128
  float mean = part[t] * (1.f / N_ENTITY);
  float var = part[128 + t] * (1.f / N_ENTITY) - mean * mean;
  float scale = gamma[t] * (1.f / 3.f) * rsqrtf(var * (1.f / 9.f) + BN_EPS);
  ksh[t] = scale;
  ksh[128 + t] = beta[t] - mean * scale;
}

__global__ void k_final(float* __restrict__ out, const float* __restrict__ ksh) {
  const size_t i4 = ((size_t)blockIdx.x * blockDim.x + threadIdx.x) * 4;
  if (i4 >= (size_t)N_ENTITY * D) return;
  const int c = (int)(i4 & 127);
  float4 v = *(float4*)(out + i4);
  v.x = fmaf(v.x, ksh[c + 0], ksh[128 + c + 0]);
  v.y = fmaf(v.y, ksh[c + 1], ksh[128 + c + 1]);
  v.z = fmaf(v.z, ksh[c + 2], ksh[128 + c + 2]);
  v.w = fmaf(v.w, ksh[c + 3], ksh[128 + c + 3]);
  *(float4*)(out + i4) = v;
}

// ---------------- host launcher ----------------
extern "C" void kernel_launch(void* const* d_in, const int* in_sizes, int n_in,
                              void* d_out, int out_size, void* d_ws, size_t ws_size,
                              hipStream_t stream) {
  const float* xe    = (const float*)d_in[0];
  const float* xr    = (const float*)d_in[1];
  const float* wl    = (const float*)d_in[2];
  const float* wf    = (const float*)d_in[3];
  const float* wb    = (const float*)d_in[4];
  const float* wrel  = (const float*)d_in[5];
  const float* sl    = (const float*)d_in[6];
  // d_in[7] = bias: cancels inside BatchNorm, unused
  const float* gamma = (const float*)d_in[8];
  const float* beta  = (const float*)d_in[9];
  const int* eidx    = (const int*)d_in[10];
  const int* etype   = (const int*)d_in[11];
  const int* esrc = eidx;
  const int* etgt = eidx + NE;

  float* outRaw = (float*)d_out;
  float* xrnew  = (float*)d_out + (size_t)N_ENTITY * D;

  float* wsf = (float*)d_ws;
  unsigned* wsu = (unsigned*)d_ws;
  unsigned* Yf  = wsu + OFF_YF;
  unsigned* Yb  = wsu + OFF_YB;
  unsigned* Zf  = wsu + OFF_ZF;
  unsigned* Zb  = wsu + OFF_ZB;
  unsigned* wpk = wsu + OFF_WPK;
  float* wrT = wsf + OFF_WRT;
  float* slw = wsf + OFF_SLW;
  unsigned* deg0 = wsu + OFF_DEG0;
  unsigned* deg1 = wsu + OFF_DEG1;
  unsigned* off0 = wsu + OFF_OFF0;
  unsigned* off1 = wsu + OFF_OFF1;
  unsigned* cur0 = wsu + OFF_CUR0;
  unsigned* cur1 = wsu + OFF_CUR1;
  float* rdeg0 = wsf + OFF_RDG0;
  float* rdeg1 = wsf + OFF_RDG1;
  uint2* el0 = (uint2*)(wsu + OFF_EL0);
  uint2* el1 = (uint2*)(wsu + OFF_EL1);
  float* part = wsf + OFF_PART;
  float* ksh  = wsf + OFF_KSH;

  // zero the degree counters (contiguous) and BN partials
  hipMemsetAsync(deg0, 0, 2 * 50048 * sizeof(unsigned), stream);
  hipMemsetAsync(part, 0, 256 * sizeof(float), stream);

  k_countP<<<2048, 256, 0, stream>>>(esrc, etgt, deg0, deg1);
  k_scanF<<<1, 1024, 0, stream>>>(deg0, deg1, off0, off1, cur0, cur1, rdeg0, rdeg1);
  k_fillP<<<2048, 256, 0, stream>>>(esrc, etgt, etype, rdeg0, rdeg1, cur0, cur1, el0, el1);

  k_prep<<<89, 256, 0, stream>>>(wl, wf, wb, wrel, sl, wpk, wrT, slw);
  k_xr<<<NR2 / 8, 256, 0, stream>>>(xr, wf, wb, wrT, Zf, Zb, xrnew);

  k_gemm3m<<<(N_ENTITY + 63) / 64, 256, 0, stream>>>(xe, wpk, slw, outRaw, Yf, Yb);

  k_gather<<<(N_ENTITY * 64) / 256, 256, 0, stream>>>(
      Yf, Yb, Zf, Zb, off0, off1, el0, el1, outRaw, part);

  k_stats2<<<1, 128, 0, stream>>>(part, gamma, beta, ksh);
  k_final<<<(N_ENTITY * D / 4 + 255) / 256, 256, 0, stream>>>(outRaw, ksh);
}

// Round 5
// 258.470 us; speedup vs baseline: 2.9060x; 2.9060x over previous
//
#include <hip/hip_runtime.h>

namespace {

constexpr int N_ENTITY = 50000;
constexpr int NR2      = 1000;     // 2 * num_relations
constexpr int NE       = 600000;
constexpr int D        = 128;
constexpr float BN_EPS = 1e-5f;

// ---- workspace layout (units of 4 bytes) ----
constexpr size_t OFF_YF   = 0;                     // 3,200,000 u32 (bf16 pairs)
constexpr size_t OFF_YB   = OFF_YF + 3200000;      // 3,200,000
constexpr size_t OFF_ZF   = OFF_YB + 3200000;      // 64,000 (bf16 pairs)
constexpr size_t OFF_ZB   = OFF_ZF + 64000;        // 64,000
constexpr size_t OFF_WPK  = OFF_ZB + 64000;        // 24,576 (3 x 8192, frag-packed bf16)
constexpr size_t OFF_WRT  = OFF_WPK + 24576;       // 16,384 f32 (w_rel^T)
constexpr size_t OFF_SLW  = OFF_WRT + 16384;       // 256 f32
constexpr size_t OFF_DEG0 = OFF_SLW + 256;         // 50,048
constexpr size_t OFF_DEG1 = OFF_DEG0 + 50048;      // 50,048
constexpr size_t OFF_OFF0 = OFF_DEG1 + 50048;      // 50,176
constexpr size_t OFF_OFF1 = OFF_OFF0 + 50176;      // 50,176
constexpr size_t OFF_RDG0 = OFF_OFF1 + 50176;      // 50,048 f32
constexpr size_t OFF_RDG1 = OFF_RDG0 + 50048;      // 50,048 f32
constexpr size_t OFF_PO0  = OFF_RDG1 + 50048;      // 100,096 (uint2 x 50,048)
constexpr size_t OFF_PO1  = OFF_PO0 + 100096;      // 100,096
constexpr size_t OFF_RNK0 = OFF_PO1 + 100096;      // 600,064
constexpr size_t OFF_RNK1 = OFF_RNK0 + 600064;     // 600,064
constexpr size_t OFF_EL0  = OFF_RNK1 + 600064;     // 1,200,128 (uint2 x 600,064)
constexpr size_t OFF_EL1  = OFF_EL0 + 1200128;     // 1,200,128
constexpr size_t OFF_BSUM = OFF_EL1 + 1200128;     // 512
constexpr size_t OFF_PART = OFF_BSUM + 512;        // 65,536
constexpr size_t OFF_KSH  = OFF_PART + 65536;      // 256

constexpr int SCAN_NB = (N_ENTITY + 255) / 256;    // 196

} // namespace

typedef __attribute__((ext_vector_type(8))) short bf16x8;
typedef __attribute__((ext_vector_type(4))) float f32x4;

__device__ inline unsigned f2bf(float x) {
  unsigned u = __float_as_uint(x);
  return (u + 0x7FFFu + ((u >> 16) & 1u)) >> 16;   // RNE
}
__device__ inline unsigned pack2bf(float a, float b) { return f2bf(a) | (f2bf(b) << 16); }
__device__ inline float bflo(unsigned v) { return __uint_as_float(v << 16); }
__device__ inline float bfhi(unsigned v) { return __uint_as_float(v & 0xFFFF0000u); }

// ---------------- degree counting + rank capture ----------------
__global__ void k_count(const int* __restrict__ esrc, const int* __restrict__ etgt,
                        unsigned* __restrict__ deg0, unsigned* __restrict__ deg1,
                        unsigned* __restrict__ rank0, unsigned* __restrict__ rank1) {
  int i = blockIdx.x * blockDim.x + threadIdx.x;
  if (i < NE) {
    rank0[i] = atomicAdd(&deg0[esrc[i]], 1u);
    rank1[i] = atomicAdd(&deg1[etgt[i]], 1u);
  }
}

// ---------------- prefix scan (3 kernels) ----------------
__device__ inline int wave_iscan(int v) {
#pragma unroll
  for (int d = 1; d < 64; d <<= 1) {
    int n = __shfl_up(v, d, 64);
    if ((int)(threadIdx.x & 63) >= d) v += n;
  }
  return v;
}

__global__ void k_scanA(const unsigned* __restrict__ deg0, const unsigned* __restrict__ deg1,
                        unsigned* __restrict__ off0, unsigned* __restrict__ off1,
                        float* __restrict__ rdeg0, float* __restrict__ rdeg1,
                        unsigned* __restrict__ bsum) {
  const int row = blockIdx.y;
  const unsigned* deg = row ? deg1 : deg0;
  unsigned* off = row ? off1 : off0;
  float* rdeg = row ? rdeg1 : rdeg0;
  const int i = blockIdx.x * 256 + threadIdx.x;
  int v = (i < N_ENTITY) ? (int)deg[i] : 0;
  if (i < N_ENTITY) rdeg[i] = rsqrtf((float)v);
  int incl = wave_iscan(v);
  __shared__ int wsum[4], woff[4];
  int wid = threadIdx.x >> 6;
  int lane = threadIdx.x & 63;
  if (lane == 63) wsum[wid] = incl;
  __syncthreads();
  if (threadIdx.x == 0) {
    int a = 0;
    for (int w = 0; w < 4; ++w) { woff[w] = a; a += wsum[w]; }
  }
  __syncthreads();
  int excl = incl - v + woff[wid];
  if (i < N_ENTITY) off[i] = (unsigned)excl;
  if (threadIdx.x == 255) bsum[row * 256 + blockIdx.x] = (unsigned)(excl + v);
}

__global__ void k_scanB(unsigned* __restrict__ bsum) {
  __shared__ int wsum[4], woff[4];
  for (int row = 0; row < 2; ++row) {
    int v = (threadIdx.x < SCAN_NB) ? (int)bsum[row * 256 + threadIdx.x] : 0;
    int incl = wave_iscan(v);
    int wid = threadIdx.x >> 6;
    int lane = threadIdx.x & 63;
    if (lane == 63) wsum[wid] = incl;
    __syncthreads();
    if (threadIdx.x == 0) {
      int a = 0;
      for (int w = 0; w < 4; ++w) { woff[w] = a; a += wsum[w]; }
    }
    __syncthreads();
    if (threadIdx.x < SCAN_NB) bsum[row * 256 + threadIdx.x] = (unsigned)(incl - v + woff[wid]);
    __syncthreads();
  }
}

__global__ void k_scanC(unsigned* __restrict__ off0, unsigned* __restrict__ off1,
                        const float* __restrict__ rdeg0, const float* __restrict__ rdeg1,
                        uint2* __restrict__ po0, uint2* __restrict__ po1,
                        const unsigned* __restrict__ bsum) {
  const int row = blockIdx.y;
  unsigned* off = row ? off1 : off0;
  const float* rdeg = row ? rdeg1 : rdeg0;
  uint2* po = row ? po1 : po0;
  const int i = blockIdx.x * 256 + threadIdx.x;
  unsigned add = bsum[row * 256 + blockIdx.x];
  if (i < N_ENTITY) {
    unsigned v = off[i] + add;
    off[i] = v;
    po[i] = make_uint2(v, __float_as_uint(rdeg[i]));
  }
  if (blockIdx.x == 0 && threadIdx.x == 0) off[N_ENTITY] = (unsigned)NE;
}

// ---------------- CSR fill: no atomics, fused 8B entries ----------------
__global__ void k_fill(const int* __restrict__ esrc, const int* __restrict__ etgt,
                       const int* __restrict__ etype,
                       const unsigned* __restrict__ rank0, const unsigned* __restrict__ rank1,
                       const uint2* __restrict__ po0, const uint2* __restrict__ po1,
                       uint2* __restrict__ el0, uint2* __restrict__ el1) {
  int i = blockIdx.x * blockDim.x + threadIdx.x;
  if (i < NE) {
    int s = esrc[i], t = etgt[i], et = etype[i];
    uint2 a = po0[s], b = po1[t];
    float w = __uint_as_float(a.y) * __uint_as_float(b.y);
    unsigned wbits = __float_as_uint(w);
    el0[a.x + rank0[i]] = make_uint2(((unsigned)t << 10) | (unsigned)(2 * et + 1), wbits);
    el1[b.x + rank1[i]] = make_uint2(((unsigned)s << 10) | (unsigned)(2 * et), wbits);
  }
}

// ---------------- fused prep: w_rel transpose + self_loop@w_loop + weight frag-pack ----------------
__global__ void k_prep(const float* __restrict__ wl, const float* __restrict__ wf,
                       const float* __restrict__ wb, const float* __restrict__ wrel,
                       const float* __restrict__ sl,
                       unsigned* __restrict__ wpk, float* __restrict__ wrT,
                       float* __restrict__ slw) {
  const int b = blockIdx.x;
  const int t = threadIdx.x;
  if (b < 64) {
    int i = b * 256 + t;
    wrT[(i & 127) * D + (i >> 7)] = wrel[i];
  } else if (b == 64) {
    if (t < 128) {
      float a = 0.f;
      for (int k = 0; k < D; ++k) a = fmaf(sl[k], wl[k * D + t], a);
      slw[t] = a;
    }
  } else {
    int idx = (b - 65) * 256 + t;   // < 6144
    int w = idx / 2048, rem = idx % 2048;
    int frag = rem / 64, l = rem % 64;
    int ct = frag >> 2, kf = frag & 3;
    const float* W = (w == 0) ? wl : (w == 1) ? wf : wb;
    int krow = kf * 32 + (l >> 4) * 8;
    int col = ct * 16 + (l & 15);
    unsigned base = (unsigned)(w * 8192 + (frag * 64 + l) * 4);
#pragma unroll
    for (int j = 0; j < 8; j += 2) {
      float a = W[(krow + j) * D + col];
      float bb = W[(krow + j + 1) * D + col];
      wpk[base + (j >> 1)] = pack2bf(a, bb);
    }
  }
}

// ---------------- small GEMM: x_r @ {w_fwd, w_bwd, w_rel^T} ----------------
__global__ __launch_bounds__(256) void k_xr(
    const float* __restrict__ xr, const float* __restrict__ wf,
    const float* __restrict__ wb, const float* __restrict__ wrT,
    unsigned* __restrict__ Zf, unsigned* __restrict__ Zb, float* __restrict__ xrnew) {
  __shared__ float xs[8 * 132];
  const int t = threadIdx.x;
  const int tile = blockIdx.x * 8;
  for (int f = t * 4; f < 8 * 128; f += 1024) {
    int rr = f >> 7, kk = f & 127;
    *(float4*)(xs + rr * 132 + kk) = *(const float4*)(xr + (size_t)(tile + rr) * D + kk);
  }
  __syncthreads();
  const int c4 = (t & 31) * 4;
  const int rs = t >> 5;  // 0..7
  const int row = tile + rs;
  float4 af = make_float4(0, 0, 0, 0), ab = make_float4(0, 0, 0, 0), ar = make_float4(0, 0, 0, 0);
#pragma unroll 4
  for (int k = 0; k < 128; ++k) {
    float x = xs[rs * 132 + k];
    float4 f4 = *(const float4*)(wf + k * D + c4);
    float4 b4 = *(const float4*)(wb + k * D + c4);
    float4 r4 = *(const float4*)(wrT + k * D + c4);
    af.x = fmaf(x, f4.x, af.x); af.y = fmaf(x, f4.y, af.y);
    af.z = fmaf(x, f4.z, af.z); af.w = fmaf(x, f4.w, af.w);
    ab.x = fmaf(x, b4.x, ab.x); ab.y = fmaf(x, b4.y, ab.y);
    ab.z = fmaf(x, b4.z, ab.z); ab.w = fmaf(x, b4.w, ab.w);
    ar.x = fmaf(x, r4.x, ar.x); ar.y = fmaf(x, r4.y, ar.y);
    ar.z = fmaf(x, r4.z, ar.z); ar.w = fmaf(x, r4.w, ar.w);
  }
  uint2 pf = make_uint2(pack2bf(af.x, af.y), pack2bf(af.z, af.w));
  uint2 pb = make_uint2(pack2bf(ab.x, ab.y), pack2bf(ab.z, ab.w));
  *(uint2*)(Zf + (size_t)row * 64 + (c4 >> 1)) = pf;
  *(uint2*)(Zb + (size_t)row * 64 + (c4 >> 1)) = pb;
  *(float4*)(xrnew + (size_t)row * D + c4) = ar;
}

// ---------------- big GEMM via MFMA: x_e @ {w_loop, w_fwd, w_bwd} ----------------
__global__ __launch_bounds__(256) void k_gemm3m(
    const float* __restrict__ xe, const unsigned* __restrict__ wpk,
    const float* __restrict__ slw, float* __restrict__ outRaw,
    unsigned* __restrict__ Yf, unsigned* __restrict__ Yb) {
  __shared__ float lds[64 * 140];
  const int tid = threadIdx.x;
  const int wv = tid >> 6, l = tid & 63;
  const int tile = blockIdx.x * 64;
  const int arow = tile + wv * 16 + (l & 15);
  const int arc = (arow < N_ENTITY) ? arow : (N_ENTITY - 1);
  const int kbase = (l >> 4) * 8;

  bf16x8 a[4];
#pragma unroll
  for (int kf = 0; kf < 4; ++kf) {
    const float* src = xe + (size_t)arc * D + kf * 32 + kbase;
    float4 lo = *(const float4*)(src);
    float4 hi = *(const float4*)(src + 4);
    union { bf16x8 v; unsigned u[4]; } cv;
    cv.u[0] = pack2bf(lo.x, lo.y);
    cv.u[1] = pack2bf(lo.z, lo.w);
    cv.u[2] = pack2bf(hi.x, hi.y);
    cv.u[3] = pack2bf(hi.z, hi.w);
    a[kf] = cv.v;
  }

  for (int widx = 0; widx < 3; ++widx) {
    const unsigned* wbase = wpk + widx * 8192;
#pragma unroll
    for (int ct = 0; ct < 8; ++ct) {
      f32x4 acc = {0.f, 0.f, 0.f, 0.f};
#pragma unroll
      for (int kf = 0; kf < 4; ++kf) {
        const bf16x8 b = *(const bf16x8*)(wbase + ((ct * 4 + kf) * 64 + l) * 4);
        acc = __builtin_amdgcn_mfma_f32_16x16x32_bf16(a[kf], b, acc, 0, 0, 0);
      }
      const int rbase = wv * 16 + (l >> 4) * 4;
      const int cc = ct * 16 + (l & 15);
#pragma unroll
      for (int j = 0; j < 4; ++j) lds[(rbase + j) * 140 + cc] = acc[j];
    }
    __syncthreads();
    for (int f = tid; f < 64 * 32; f += 256) {
      int row = f >> 5, c4 = (f & 31) * 4;
      int g = tile + row;
      if (g < N_ENTITY) {
        float4 v = *(float4*)(lds + row * 140 + c4);
        if (widx == 0) {
          float4 s = *(const float4*)(slw + c4);
          float4 o = make_float4(v.x - s.x, v.y - s.y, v.z - s.z, v.w - s.w);
          *(float4*)(outRaw + (size_t)g * D + c4) = o;
        } else {
          uint2 p = make_uint2(pack2bf(v.x, v.y), pack2bf(v.z, v.w));
          unsigned* dst = ((widx == 1) ? Yf : Yb) + (size_t)g * 64 + (c4 >> 1);
          *(uint2*)dst = p;
        }
      }
    }
    __syncthreads();
  }
}

// ---------------- per-entity edge aggregation, 4x unrolled ----------------
__device__ inline void gather_dir(const unsigned* __restrict__ Y,
                                  const unsigned* __restrict__ Z,
                                  const uint2* __restrict__ el,
                                  unsigned b, unsigned e, int lane, float2& acc) {
  for (unsigned base = b; base < e; base += 64) {
    int cnt = (int)((e - base < 64u) ? (e - base) : 64u);
    uint2 ed = make_uint2(0u, 0u);
    if (lane < cnt) ed = el[base + lane];
    int i = 0;
    for (; i + 4 <= cnt; i += 4) {
      unsigned pk0 = __shfl(ed.x, i, 64);     float w0 = __uint_as_float(__shfl(ed.y, i, 64));
      unsigned pk1 = __shfl(ed.x, i + 1, 64); float w1 = __uint_as_float(__shfl(ed.y, i + 1, 64));
      unsigned pk2 = __shfl(ed.x, i + 2, 64); float w2 = __uint_as_float(__shfl(ed.y, i + 2, 64));
      unsigned pk3 = __shfl(ed.x, i + 3, 64); float w3 = __uint_as_float(__shfl(ed.y, i + 3, 64));
      unsigned y0 = Y[(size_t)(pk0 >> 10) * 64 + lane];
      unsigned z0 = Z[(size_t)(pk0 & 1023u) * 64 + lane];
      unsigned y1 = Y[(size_t)(pk1 >> 10) * 64 + lane];
      unsigned z1 = Z[(size_t)(pk1 & 1023u) * 64 + lane];
      unsigned y2 = Y[(size_t)(pk2 >> 10) * 64 + lane];
      unsigned z2 = Z[(size_t)(pk2 & 1023u) * 64 + lane];
      unsigned y3 = Y[(size_t)(pk3 >> 10) * 64 + lane];
      unsigned z3 = Z[(size_t)(pk3 & 1023u) * 64 + lane];
      acc.x = fmaf(w0, bflo(y0) - bflo(z0), acc.x);
      acc.y = fmaf(w0, bfhi(y0) - bfhi(z0), acc.y);
      acc.x = fmaf(w1, bflo(y1) - bflo(z1), acc.x);
      acc.y = fmaf(w1, bfhi(y1) - bfhi(z1), acc.y);
      acc.x = fmaf(w2, bflo(y2) - bflo(z2), acc.x);
      acc.y = fmaf(w2, bfhi(y2) - bfhi(z2), acc.y);
      acc.x = fmaf(w3, bflo(y3) - bflo(z3), acc.x);
      acc.y = fmaf(w3, bfhi(y3) - bfhi(z3), acc.y);
    }
    for (; i < cnt; ++i) {
      unsigned pk = __shfl(ed.x, i, 64);
      float w = __uint_as_float(__shfl(ed.y, i, 64));
      unsigned y = Y[(size_t)(pk >> 10) * 64 + lane];
      unsigned z = Z[(size_t)(pk & 1023u) * 64 + lane];
      acc.x = fmaf(w, bflo(y) - bflo(z), acc.x);
      acc.y = fmaf(w, bfhi(y) - bfhi(z), acc.y);
    }
  }
}

__global__ __launch_bounds__(256) void k_gather(
    const unsigned* __restrict__ Yf, const unsigned* __restrict__ Yb,
    const unsigned* __restrict__ Zf, const unsigned* __restrict__ Zb,
    const unsigned* __restrict__ off0, const unsigned* __restrict__ off1,
    const uint2* __restrict__ el0, const uint2* __restrict__ el1,
    float* __restrict__ out) {
  const int lane = threadIdx.x & 63;
  const int n = (int)((blockIdx.x * blockDim.x + threadIdx.x) >> 6);
  if (n >= N_ENTITY) return;
  const size_t rowoff = (size_t)n * D + lane * 2;
  float2 acc = *(const float2*)(out + rowoff);

  gather_dir(Yf, Zf, el1, off1[n], off1[n + 1], lane, acc);
  gather_dir(Yb, Zb, el0, off0[n], off0[n + 1], lane, acc);

  *(float2*)(out + rowoff) = acc;
}

// ---------------- BN statistics + finalize ----------------
__global__ void k_stats1(const float* __restrict__ out, float* __restrict__ part) {
  const int t = threadIdx.x;  // 128
  float s = 0.f, sq = 0.f;
  for (int r = blockIdx.x; r < N_ENTITY; r += gridDim.x) {
    float v = out[(size_t)r * D + t];
    s += v;
    sq = fmaf(v, v, sq);
  }
  part[blockIdx.x * 256 + t] = s;
  part[blockIdx.x * 256 + 128 + t] = sq;
}

__global__ void k_stats2(const float* __restrict__ part, const float* __restrict__ gamma,
                         const float* __restrict__ beta, float* __restrict__ ksh) {
  const int t = threadIdx.x;  // 128
  float s = 0.f, sq = 0.f;
  for (int b = 0; b < 256; ++b) {
    s += part[b * 256 + t];
    sq += part[b * 256 + 128 + t];
  }
  float mean = s * (1.f / N_ENTITY);
  float var = sq * (1.f / N_ENTITY) - mean * mean;
  float scale = gamma[t] * (1.f / 3.f) * rsqrtf(var * (1.f / 9.f) + BN_EPS);
  ksh[t] = scale;
  ksh[128 + t] = beta[t] - mean * scale;
}

__global__ void k_final(float* __restrict__ out, const float* __restrict__ ksh) {
  const size_t i4 = ((size_t)blockIdx.x * blockDim.x + threadIdx.x) * 4;
  if (i4 >= (size_t)N_ENTITY * D) return;
  const int c = (int)(i4 & 127);
  float4 v = *(float4*)(out + i4);
  v.x = fmaf(v.x, ksh[c + 0], ksh[128 + c + 0]);
  v.y = fmaf(v.y, ksh[c + 1], ksh[128 + c + 1]);
  v.z = fmaf(v.z, ksh[c + 2], ksh[128 + c + 2]);
  v.w = fmaf(v.w, ksh[c + 3], ksh[128 + c + 3]);
  *(float4*)(out + i4) = v;
}

// ---------------- host launcher ----------------
extern "C" void kernel_launch(void* const* d_in, const int* in_sizes, int n_in,
                              void* d_out, int out_size, void* d_ws, size_t ws_size,
                              hipStream_t stream) {
  const float* xe    = (const float*)d_in[0];
  const float* xr    = (const float*)d_in[1];
  const float* wl    = (const float*)d_in[2];
  const float* wf    = (const float*)d_in[3];
  const float* wb    = (const float*)d_in[4];
  const float* wrel  = (const float*)d_in[5];
  const float* sl    = (const float*)d_in[6];
  // d_in[7] = bias: cancels inside BatchNorm, unused
  const float* gamma = (const float*)d_in[8];
  const float* beta  = (const float*)d_in[9];
  const int* eidx    = (const int*)d_in[10];
  const int* etype   = (const int*)d_in[11];
  const int* esrc = eidx;
  const int* etgt = eidx + NE;

  float* outRaw = (float*)d_out;
  float* xrnew  = (float*)d_out + (size_t)N_ENTITY * D;

  float* wsf = (float*)d_ws;
  unsigned* wsu = (unsigned*)d_ws;
  unsigned* Yf  = wsu + OFF_YF;
  unsigned* Yb  = wsu + OFF_YB;
  unsigned* Zf  = wsu + OFF_ZF;
  unsigned* Zb  = wsu + OFF_ZB;
  unsigned* wpk = wsu + OFF_WPK;
  float* wrT = wsf + OFF_WRT;
  float* slw = wsf + OFF_SLW;
  unsigned* deg0 = wsu + OFF_DEG0;
  unsigned* deg1 = wsu + OFF_DEG1;
  unsigned* off0 = wsu + OFF_OFF0;
  unsigned* off1 = wsu + OFF_OFF1;
  float* rdeg0 = wsf + OFF_RDG0;
  float* rdeg1 = wsf + OFF_RDG1;
  uint2* po0 = (uint2*)(wsu + OFF_PO0);
  uint2* po1 = (uint2*)(wsu + OFF_PO1);
  unsigned* rank0 = wsu + OFF_RNK0;
  unsigned* rank1 = wsu + OFF_RNK1;
  uint2* el0 = (uint2*)(wsu + OFF_EL0);
  uint2* el1 = (uint2*)(wsu + OFF_EL1);
  unsigned* bsum = wsu + OFF_BSUM;
  float* part = wsf + OFF_PART;
  float* ksh  = wsf + OFF_KSH;

  // zero the degree counters (deg0 and deg1 are contiguous)
  hipMemsetAsync(deg0, 0, 2 * 50048 * sizeof(unsigned), stream);

  const int EB = (NE + 255) / 256;
  k_count<<<EB, 256, 0, stream>>>(esrc, etgt, deg0, deg1, rank0, rank1);

  dim3 gscan(SCAN_NB, 2);
  k_scanA<<<gscan, 256, 0, stream>>>(deg0, deg1, off0, off1, rdeg0, rdeg1, bsum);
  k_scanB<<<1, 256, 0, stream>>>(bsum);
  k_scanC<<<gscan, 256, 0, stream>>>(off0, off1, rdeg0, rdeg1, po0, po1, bsum);
  k_fill<<<EB, 256, 0, stream>>>(esrc, etgt, etype, rank0, rank1, po0, po1, el0, el1);

  k_prep<<<89, 256, 0, stream>>>(wl, wf, wb, wrel, sl, wpk, wrT, slw);
  k_xr<<<NR2 / 8, 256, 0, stream>>>(xr, wf, wb, wrT, Zf, Zb, xrnew);

  k_gemm3m<<<(N_ENTITY + 63) / 64, 256, 0, stream>>>(xe, wpk, slw, outRaw, Yf, Yb);

  k_gather<<<(N_ENTITY * 64 + 255) / 256, 256, 0, stream>>>(
      Yf, Yb, Zf, Zb, off0, off1, el0, el1, outRaw);

  k_stats1<<<256, 128, 0, stream>>>(outRaw, part);
  k_stats2<<<1, 128, 0, stream>>>(part, gamma, beta, ksh);
  k_final<<<(N_ENTITY * D / 4 + 255) / 256, 256, 0, stream>>>(outRaw, ksh);
}